// Round 11
// baseline (61.487 us; speedup 1.0000x reference)
//
#include <hip/hip_runtime.h>
#include <cstdint>

#define BDIM 4
#define NDIM 2048
#define FDIM 64
#define CDIM 64
#define LDIM 3
#define KTOT (NDIM * LDIM)   /* 6144 */
#define BK 256
#define NSTEP (KTOT / BK)    /* 24 */
#define KB (KTOT / 32)       /* 192 */
#define BSTEP (8 * 2048)     /* B shorts per step */
#define BTOT (KB * 2048)     /* B shorts per batch */

typedef __attribute__((ext_vector_type(4))) float f32x4;
typedef __attribute__((ext_vector_type(8))) short s16x8;
typedef __attribute__((ext_vector_type(4))) unsigned int u32x4;

__device__ __forceinline__ unsigned short f2bf(float x) {
  union { float f; uint32_t u; } v; v.f = x;
  uint32_t r = v.u + 0x7FFFu + ((v.u >> 16) & 1u);
  return (unsigned short)(r >> 16);
}

__device__ __forceinline__ uint32_t cvtpk(float lo, float hi) {
  uint32_t r;
  asm("v_cvt_pk_bf16_f32 %0, %1, %2" : "=v"(r) : "v"(lo), "v"(hi));
  return r;
}

// ---------------------------------------------------------------------------
// K1: S[b,i,c] = sum_f h0[c,f] V[b,i,f]   (fp32, ws)
//     Ut3[b][kb][cw][g][q][e] = U[b][c=cw*16+q][k=kb*32+g*8+e]  (bf16, ws)
//     where U[b][c][k=j*3+l] = sum_f h_{1+l}[c,f] V[b,j,f].
// Layout: k2's per-(kb,cw) wave B-load is 1 KB contiguous (lane*16B).
// MFMA 16x16x32 lane maps (verified R1-R10, absmax 0.5):
//   A: row=l&15, k=(l>>4)*8+e ; B: col=l&15, same k ; D: col=l&15, row=(l>>4)*4+rr
// ---------------------------------------------------------------------------
__global__ __launch_bounds__(64) void k1_precompute(
    const float* __restrict__ V, const float* __restrict__ hw,
    float* __restrict__ S, unsigned short* __restrict__ Ut3) {
  const int j0 = blockIdx.x * 16;
  const int le = blockIdx.y;
  const int b  = blockIdx.z;
  const int lane = threadIdx.x;
  const int q = lane & 15, g = lane >> 4;

  const float* vrow = V + ((size_t)(b * NDIM + j0 + q)) * FDIM + g * 8;
  f32x4 va0 = *(const f32x4*)(vrow);
  f32x4 va1 = *(const f32x4*)(vrow + 4);
  f32x4 va2 = *(const f32x4*)(vrow + 32);
  f32x4 va3 = *(const f32x4*)(vrow + 36);
  s16x8 a0, a1;
#pragma unroll
  for (int e = 0; e < 4; ++e) {
    a0[e]     = (short)f2bf(va0[e]);
    a0[e + 4] = (short)f2bf(va1[e]);
    a1[e]     = (short)f2bf(va2[e]);
    a1[e + 4] = (short)f2bf(va3[e]);
  }

  const float* hbase = hw + (size_t)le * CDIM * FDIM;
#pragma unroll
  for (int ct = 0; ct < 4; ++ct) {
    const float* hrow = hbase + (size_t)(ct * 16 + q) * FDIM + g * 8;
    f32x4 hb0 = *(const f32x4*)(hrow);
    f32x4 hb1 = *(const f32x4*)(hrow + 4);
    f32x4 hb2 = *(const f32x4*)(hrow + 32);
    f32x4 hb3 = *(const f32x4*)(hrow + 36);
    s16x8 b0, b1;
#pragma unroll
    for (int e = 0; e < 4; ++e) {
      b0[e]     = (short)f2bf(hb0[e]);
      b0[e + 4] = (short)f2bf(hb1[e]);
      b1[e]     = (short)f2bf(hb2[e]);
      b1[e + 4] = (short)f2bf(hb3[e]);
    }
    f32x4 acc = {0.f, 0.f, 0.f, 0.f};
    acc = __builtin_amdgcn_mfma_f32_16x16x32_bf16(a0, b0, acc, 0, 0, 0);
    acc = __builtin_amdgcn_mfma_f32_16x16x32_bf16(a1, b1, acc, 0, 0, 0);
    if (le == 0) {
#pragma unroll
      for (int rr = 0; rr < 4; ++rr) {
        int j = j0 + g * 4 + rr;
        S[((size_t)b * NDIM + j) * CDIM + ct * 16 + q] = acc[rr];
      }
    } else {
#pragma unroll
      for (int rr = 0; rr < 4; ++rr) {
        int j = j0 + g * 4 + rr;
        int k = j * 3 + (le - 1);
        int kb = k >> 5, gg = (k >> 3) & 3, ee = k & 7;
        size_t off = ((size_t)b * KB + kb) * 2048 + (size_t)ct * 512 +
                     (size_t)gg * 128 + (size_t)q * 8 + ee;
        Ut3[off] = f2bf(acc[rr]);
      }
    }
  }
}

// ---------------------------------------------------------------------------
// K2: out[b, i0..i0+31, :] = relu(S + A[b,i0:i0+32,:] @ U[b])
// R10 base (best: M=32, 8 waves, BK=256, ring-2x32KB, 1KB GLL granules,
// 1 block/CU, counted waits) + two changes:
//  1) NT cache policy (aux=2) on A staging: A is pure streaming; stop
//     allocating it in L2/L3 -> B/Ut3 stays cache-hot, no thrash.
//  2) Split GLL issue 2+2 (pos0: GLLab(s+1); mid: GLLcd(s+1)) so the VMEM
//     queue never empties across a step.
// Issue order per step: pos0 [B_H1(s)x4, GLLab(s+1)x2] wait1=vmcnt(6)
//   (retires GLLcd(s)+H0(s) => A(s) in LDS, B_H0(s) in regs);
//   mid [GLLcd(s+1)x2, B_H0(s+1)x4] wait2=vmcnt(8) (retires B_H1(s);
//   all 8 step-(s+1) ops stay in flight). NEVER vmcnt(0) in the loop.
// Race: GLL(s+1) writes slot (s+1)&1, read at step s-1; its readers passed
// end-barrier(s-1) < pos0 of s. Two barriers/step as R10.
// ---------------------------------------------------------------------------
__global__ __launch_bounds__(512) void k2_main(
    const float* __restrict__ A, const unsigned short* __restrict__ Ut3,
    const float* __restrict__ S, float* __restrict__ out) {
  __shared__ float Abuf[2][8192];  // 2 slots x 32 rows x 256 floats = 64 KB

  const int bid = blockIdx.x;
  const int swz = (bid & 7) * 32 + (bid >> 3);  // XCD-chunked, 256 % 8 == 0
  const int b   = swz >> 6;
  const int i0  = (swz & 63) * 32;
  const int tid = threadIdx.x;
  const int lane = tid & 63, w = tid >> 6;
  const int q = lane & 15, g = lane >> 4, q7 = q & 7;
  const int wr = w >> 2, wc = w & 3;

  // A row bases: wave w stages rows 4w..4w+3, 1 KB contiguous per GLL;
  // 16B granules XOR-preswizzled by row&7 (involution; read applies same).
  const float* agb[4];
#pragma unroll
  for (int t = 0; t < 4; ++t) {
    int r = 4 * w + t;
    agb[t] = A + ((size_t)(b * NDIM + i0 + r)) * KTOT + ((lane ^ (r & 7)) * 4);
  }
  int akoff = 0;  // k-offset in floats

  // B base: col group cw=wc; per step 8 kb x 1KB contiguous
  const unsigned short* bgb =
      Ut3 + (size_t)b * BTOT + (size_t)wc * 512 + (size_t)lane * 8;
  int bkoff = 0;  // offset in shorts

  // LDS dest: wave-uniform base + lane*16B (GLL requirement)
  float* ldsw = &Abuf[0][0] + w * 1024 + lane * 4;

  // aux=2 -> CPol NT (non-temporal): no L2/L3 allocation for streamed A
#define GLLAB(slot)                                                           \
  do {                                                                        \
    __builtin_amdgcn_global_load_lds(                                         \
        (__attribute__((address_space(1))) void*)(agb[0] + akoff),            \
        (__attribute__((address_space(3))) void*)(ldsw + (slot) * 8192), 16, 0, 2); \
    __builtin_amdgcn_global_load_lds(                                         \
        (__attribute__((address_space(1))) void*)(agb[1] + akoff),            \
        (__attribute__((address_space(3))) void*)(ldsw + (slot) * 8192 + 256), 16, 0, 2); \
  } while (0)

#define GLLCD(slot)                                                           \
  do {                                                                        \
    __builtin_amdgcn_global_load_lds(                                         \
        (__attribute__((address_space(1))) void*)(agb[2] + akoff),            \
        (__attribute__((address_space(3))) void*)(ldsw + (slot) * 8192 + 512), 16, 0, 2); \
    __builtin_amdgcn_global_load_lds(                                         \
        (__attribute__((address_space(1))) void*)(agb[3] + akoff),            \
        (__attribute__((address_space(3))) void*)(ldsw + (slot) * 8192 + 768), 16, 0, 2); \
  } while (0)

#define LDB(BW, HB)                                                           \
  do {                                                                        \
    _Pragma("unroll")                                                         \
    for (int t = 0; t < 4; ++t)                                               \
      BW[t] = *(const s16x8*)(bgb + bkoff + (size_t)((HB) + t) * 2048);       \
  } while (0)

#define HALF(half, BR)                                                        \
  do {                                                                        \
    const float* rowp = &Abuf[s & 1][0] + (wr * 16 + q) * 256;                \
    _Pragma("unroll")                                                         \
    for (int kk = 0; kk < 4; ++kk) {                                          \
      int kg = (half) * 4 + kk;                                               \
      f32x4 a0 = *(const f32x4*)(rowp + ((kg * 8 + ((2 * g) ^ q7)) << 2));    \
      f32x4 a1 = *(const f32x4*)(rowp + ((kg * 8 + ((2 * g + 1) ^ q7)) << 2));\
      u32x4 wv;                                                               \
      wv[0] = cvtpk(a0[0], a0[1]); wv[1] = cvtpk(a0[2], a0[3]);               \
      wv[2] = cvtpk(a1[0], a1[1]); wv[3] = cvtpk(a1[2], a1[3]);               \
      if (kk & 1)                                                             \
        accB = __builtin_amdgcn_mfma_f32_16x16x32_bf16(                       \
            __builtin_bit_cast(s16x8, wv), BR[kk], accB, 0, 0, 0);            \
      else                                                                    \
        accA = __builtin_amdgcn_mfma_f32_16x16x32_bf16(                       \
            __builtin_bit_cast(s16x8, wv), BR[kk], accA, 0, 0, 0);            \
    }                                                                         \
  } while (0)

  f32x4 accA = {0.f, 0.f, 0.f, 0.f}, accB = {0.f, 0.f, 0.f, 0.f};
  s16x8 bA[4], bB[4];

  // prologue: GLLab(0), GLLcd(0), B_H0(0)->bA ; akoff -> window 1
  GLLAB(0); GLLCD(0); akoff = BK;
  LDB(bA, 0);

  for (int s = 0; s < NSTEP; ++s) {
    // --- pos0: [B_H1(s)x4, GLLab(s+1)x2] ---
    LDB(bB, 4);
    GLLAB((s + 1) & 1);
    if (s + 1 < NSTEP) bkoff += BSTEP;            // -> step s+1's B base
    asm volatile("s_waitcnt vmcnt(6)" ::: "memory");  // A(s)+B_H0(s) done
    __builtin_amdgcn_sched_barrier(0);
    __builtin_amdgcn_s_barrier();                 // A(s) visible to all waves
    __builtin_amdgcn_sched_barrier(0);
    HALF(0, bA);                                  // kb 0..3
    // --- mid: [GLLcd(s+1)x2, B_H0(s+1)x4] ---
    GLLCD((s + 1) & 1);
    if (s + 2 < NSTEP) akoff += BK;               // tail: freeze (dead slot)
    LDB(bA, 0);                                   // B_H0(s+1) (s=23: dead)
    asm volatile("s_waitcnt vmcnt(8)" ::: "memory");  // B_H1(s) done;
    __builtin_amdgcn_sched_barrier(0);                // step-(s+1) ops queued
    HALF(1, bB);                                  // kb 4..7
    __builtin_amdgcn_s_barrier();                 // end-of-step: slot guard
  }
#undef HALF
#undef GLLAB
#undef GLLCD
#undef LDB

  // drain overrun glls before s_endpgm (LDS may be re-assigned)
  asm volatile("s_waitcnt vmcnt(0)" ::: "memory");

  // epilogue: add self-term, relu, direct store
  f32x4 acc = accA + accB;
  const int c = wc * 16 + q;
#pragma unroll
  for (int rr = 0; rr < 4; ++rr) {
    int i = i0 + wr * 16 + g * 4 + rr;
    size_t idx = ((size_t)(b * NDIM) + i) * CDIM + c;
    float v = acc[rr] + S[idx];
    out[idx] = v > 0.f ? v : 0.f;
  }
}

extern "C" void kernel_launch(void* const* d_in, const int* in_sizes, int n_in,
                              void* d_out, int out_size, void* d_ws, size_t ws_size,
                              hipStream_t stream) {
  const float* V  = (const float*)d_in[0];
  const float* A  = (const float*)d_in[1];
  const float* hw = (const float*)d_in[2];
  float* out = (float*)d_out;

  float* S = (float*)d_ws;
  unsigned short* Ut3 =
      (unsigned short*)((char*)d_ws + (size_t)BDIM * NDIM * CDIM * sizeof(float));

  k1_precompute<<<dim3(NDIM / 16, LDIM + 1, BDIM), 64, 0, stream>>>(V, hw, S, Ut3);
  k2_main<<<dim3((NDIM / 32) * BDIM), 512, 0, stream>>>(A, Ut3, S, out);
}

// Round 12
// 48.860 us; speedup vs baseline: 1.2584x; 1.2584x over previous
//
#include <hip/hip_runtime.h>
#include <cstdint>

#define BDIM 4
#define NDIM 2048
#define FDIM 64
#define CDIM 64
#define LDIM 3
#define KTOT (NDIM * LDIM)   /* 6144 */
#define BK 256
#define NSTEP 12             /* steps per K-half: 3072/256 */
#define KB (KTOT / 32)       /* 192 kb-blocks total */
#define BSTEP (8 * 2048)     /* B shorts per step */
#define BTOT (KB * 2048)     /* B shorts per batch */
#define BHALF (96 * 2048)    /* B shorts per K-half */
#define TOTE (BDIM * NDIM * CDIM) /* 524288 output elements */

typedef __attribute__((ext_vector_type(4))) float f32x4;
typedef __attribute__((ext_vector_type(8))) short s16x8;
typedef __attribute__((ext_vector_type(4))) unsigned int u32x4;

__device__ __forceinline__ unsigned short f2bf(float x) {
  union { float f; uint32_t u; } v; v.f = x;
  uint32_t r = v.u + 0x7FFFu + ((v.u >> 16) & 1u);
  return (unsigned short)(r >> 16);
}

__device__ __forceinline__ uint32_t cvtpk(float lo, float hi) {
  uint32_t r;
  asm("v_cvt_pk_bf16_f32 %0, %1, %2" : "=v"(r) : "v"(lo), "v"(hi));
  return r;
}

// ---------------------------------------------------------------------------
// K1: S[b,i,c] = sum_f h0[c,f] V[b,i,f]   (fp32, ws)
//     Ut3[b][kb][cw][g][q][e] = U[b][c=cw*16+q][k=kb*32+g*8+e]  (bf16, ws)
// MFMA 16x16x32 lane maps (verified R1-R11, absmax 0.5):
//   A: row=l&15, k=(l>>4)*8+e ; B: col=l&15, same k ; D: col=l&15, row=(l>>4)*4+rr
// ---------------------------------------------------------------------------
__global__ __launch_bounds__(64) void k1_precompute(
    const float* __restrict__ V, const float* __restrict__ hw,
    float* __restrict__ S, unsigned short* __restrict__ Ut3) {
  const int j0 = blockIdx.x * 16;
  const int le = blockIdx.y;
  const int b  = blockIdx.z;
  const int lane = threadIdx.x;
  const int q = lane & 15, g = lane >> 4;

  const float* vrow = V + ((size_t)(b * NDIM + j0 + q)) * FDIM + g * 8;
  f32x4 va0 = *(const f32x4*)(vrow);
  f32x4 va1 = *(const f32x4*)(vrow + 4);
  f32x4 va2 = *(const f32x4*)(vrow + 32);
  f32x4 va3 = *(const f32x4*)(vrow + 36);
  s16x8 a0, a1;
#pragma unroll
  for (int e = 0; e < 4; ++e) {
    a0[e]     = (short)f2bf(va0[e]);
    a0[e + 4] = (short)f2bf(va1[e]);
    a1[e]     = (short)f2bf(va2[e]);
    a1[e + 4] = (short)f2bf(va3[e]);
  }

  const float* hbase = hw + (size_t)le * CDIM * FDIM;
#pragma unroll
  for (int ct = 0; ct < 4; ++ct) {
    const float* hrow = hbase + (size_t)(ct * 16 + q) * FDIM + g * 8;
    f32x4 hb0 = *(const f32x4*)(hrow);
    f32x4 hb1 = *(const f32x4*)(hrow + 4);
    f32x4 hb2 = *(const f32x4*)(hrow + 32);
    f32x4 hb3 = *(const f32x4*)(hrow + 36);
    s16x8 b0, b1;
#pragma unroll
    for (int e = 0; e < 4; ++e) {
      b0[e]     = (short)f2bf(hb0[e]);
      b0[e + 4] = (short)f2bf(hb1[e]);
      b1[e]     = (short)f2bf(hb2[e]);
      b1[e + 4] = (short)f2bf(hb3[e]);
    }
    f32x4 acc = {0.f, 0.f, 0.f, 0.f};
    acc = __builtin_amdgcn_mfma_f32_16x16x32_bf16(a0, b0, acc, 0, 0, 0);
    acc = __builtin_amdgcn_mfma_f32_16x16x32_bf16(a1, b1, acc, 0, 0, 0);
    if (le == 0) {
#pragma unroll
      for (int rr = 0; rr < 4; ++rr) {
        int j = j0 + g * 4 + rr;
        S[((size_t)b * NDIM + j) * CDIM + ct * 16 + q] = acc[rr];
      }
    } else {
#pragma unroll
      for (int rr = 0; rr < 4; ++rr) {
        int j = j0 + g * 4 + rr;
        int k = j * 3 + (le - 1);
        int kb = k >> 5, gg = (k >> 3) & 3, ee = k & 7;
        size_t off = ((size_t)b * KB + kb) * 2048 + (size_t)ct * 512 +
                     (size_t)gg * 128 + (size_t)q * 8 + ee;
        Ut3[off] = f2bf(acc[rr]);
      }
    }
  }
}

// ---------------------------------------------------------------------------
// K2: P[h][b, i0..i0+31, :] += A[b,i0:i0+32, h-half] @ U[b, h-half]
// EXACT R10 pipeline (M=32, 8 waves, BK=256, ring-2x32KB, 1KB GLL granules,
// counted vmcnt(8)/vmcnt(8), 2 barriers/step, aux=0) but K-SPLIT 2:
// grid 512 = 2 blocks/CU, each block 12 steps over half of K.
// Rationale: per-CU in-flight A doubles 32->64 KB (Little's law at 6.3 TB/s
// with ~1.2-1.5k cy loaded latency needs 30-39 KB; R10 sat at the edge),
// plus desynced-pair issue smoothing. Per-CU A:B stays 1:1.
// Partials to ws (fp32, deterministic, no atomics); k3 reduces.
// ---------------------------------------------------------------------------
__global__ __launch_bounds__(512) void k2_main(
    const float* __restrict__ A, const unsigned short* __restrict__ Ut3,
    float* __restrict__ P) {
  __shared__ float Abuf[2][8192];  // 2 slots x 32 rows x 256 floats = 64 KB

  const int bid = blockIdx.x;
  const int swz = (bid & 7) * 64 + (bid >> 3);  // XCD-chunked, 512 % 8 == 0
  const int h    = swz & 1;                     // K-half
  const int rest = swz >> 1;
  const int b    = rest >> 6;
  const int i0   = (rest & 63) * 32;
  const int tid = threadIdx.x;
  const int lane = tid & 63, w = tid >> 6;
  const int q = lane & 15, g = lane >> 4, q7 = q & 7;
  const int wr = w >> 2, wc = w & 3;

  // A row bases: wave w stages rows 4w..4w+3, 1 KB contiguous per GLL;
  // 16B granules XOR-preswizzled by row&7 (involution; read applies same).
  const float* agb[4];
#pragma unroll
  for (int t = 0; t < 4; ++t) {
    int r = 4 * w + t;
    agb[t] = A + ((size_t)(b * NDIM + i0 + r)) * KTOT + ((lane ^ (r & 7)) * 4);
  }
  int akoff = h * (KTOT / 2);  // k-offset in floats (this block's half)

  // B base: col group cw=wc, this K-half; per step 8 kb x 1KB contiguous
  const unsigned short* bgb =
      Ut3 + (size_t)b * BTOT + (size_t)wc * 512 + (size_t)lane * 8;
  int bkoff = h * BHALF;  // offset in shorts

  // LDS dest: wave-uniform base + lane*16B (GLL requirement)
  float* ldsw = &Abuf[0][0] + w * 1024 + lane * 4;

#define GLL4(slot)                                                            \
  do {                                                                        \
    __builtin_amdgcn_global_load_lds(                                         \
        (__attribute__((address_space(1))) void*)(agb[0] + akoff),            \
        (__attribute__((address_space(3))) void*)(ldsw + (slot) * 8192), 16, 0, 0); \
    __builtin_amdgcn_global_load_lds(                                         \
        (__attribute__((address_space(1))) void*)(agb[1] + akoff),            \
        (__attribute__((address_space(3))) void*)(ldsw + (slot) * 8192 + 256), 16, 0, 0); \
    __builtin_amdgcn_global_load_lds(                                         \
        (__attribute__((address_space(1))) void*)(agb[2] + akoff),            \
        (__attribute__((address_space(3))) void*)(ldsw + (slot) * 8192 + 512), 16, 0, 0); \
    __builtin_amdgcn_global_load_lds(                                         \
        (__attribute__((address_space(1))) void*)(agb[3] + akoff),            \
        (__attribute__((address_space(3))) void*)(ldsw + (slot) * 8192 + 768), 16, 0, 0); \
  } while (0)

#define LDB(BW, HB)                                                           \
  do {                                                                        \
    _Pragma("unroll")                                                         \
    for (int t = 0; t < 4; ++t)                                               \
      BW[t] = *(const s16x8*)(bgb + bkoff + (size_t)((HB) + t) * 2048);       \
  } while (0)

#define HALF(half, BR)                                                        \
  do {                                                                        \
    const float* rowp = &Abuf[s & 1][0] + (wr * 16 + q) * 256;                \
    _Pragma("unroll")                                                         \
    for (int kk = 0; kk < 4; ++kk) {                                          \
      int kg = (half) * 4 + kk;                                               \
      f32x4 a0 = *(const f32x4*)(rowp + ((kg * 8 + ((2 * g) ^ q7)) << 2));    \
      f32x4 a1 = *(const f32x4*)(rowp + ((kg * 8 + ((2 * g + 1) ^ q7)) << 2));\
      u32x4 wv;                                                               \
      wv[0] = cvtpk(a0[0], a0[1]); wv[1] = cvtpk(a0[2], a0[3]);               \
      wv[2] = cvtpk(a1[0], a1[1]); wv[3] = cvtpk(a1[2], a1[3]);               \
      if (kk & 1)                                                             \
        accB = __builtin_amdgcn_mfma_f32_16x16x32_bf16(                       \
            __builtin_bit_cast(s16x8, wv), BR[kk], accB, 0, 0, 0);            \
      else                                                                    \
        accA = __builtin_amdgcn_mfma_f32_16x16x32_bf16(                       \
            __builtin_bit_cast(s16x8, wv), BR[kk], accA, 0, 0, 0);            \
    }                                                                         \
  } while (0)

  f32x4 accA = {0.f, 0.f, 0.f, 0.f}, accB = {0.f, 0.f, 0.f, 0.f};
  s16x8 bA[4], bB[4];

  // prologue: GLL(0)x4, B_H0(0)x4 -> bA ; akoff -> window 1
  GLL4(0); akoff += BK;
  LDB(bA, 0);

  for (int s = 0; s < NSTEP; ++s) {
    // pos0: [B_H1(s)x4, GLL(s+1)x4]; vmcnt(8) retires GLL(s)+B_H0(s)
    LDB(bB, 4);
    GLL4((s + 1) & 1);
    if (s + 2 < NSTEP) akoff += BK;       // tail: freeze (dead slot re-read)
    if (s + 1 < NSTEP) bkoff += BSTEP;    // -> step s+1's B base
    asm volatile("s_waitcnt vmcnt(8)" ::: "memory");  // A(s), B_H0(s) done
    __builtin_amdgcn_sched_barrier(0);
    __builtin_amdgcn_s_barrier();         // A(s) visible to all waves
    __builtin_amdgcn_sched_barrier(0);
    HALF(0, bA);                          // kb 0..3
    LDB(bA, 0);                           // B_H0(s+1) (last step: dead)
    asm volatile("s_waitcnt vmcnt(8)" ::: "memory");  // B_H1(s) done;
    __builtin_amdgcn_sched_barrier(0);                // GLL(s+1) stays queued
    HALF(1, bB);                          // kb 4..7
    __builtin_amdgcn_s_barrier();         // end-of-step: protect slot (s+1)&1
  }
#undef HALF
#undef GLL4
#undef LDB

  // drain overrun glls before s_endpgm (LDS may be re-assigned)
  asm volatile("s_waitcnt vmcnt(0)" ::: "memory");

  // epilogue: write fp32 partial (no S, no relu) to P[h]
  f32x4 acc = accA + accB;
  float* Ph = P + (size_t)h * TOTE;
  const int c = wc * 16 + q;
#pragma unroll
  for (int rr = 0; rr < 4; ++rr) {
    int i = i0 + wr * 16 + g * 4 + rr;
    Ph[((size_t)(b * NDIM) + i) * CDIM + c] = acc[rr];
  }
}

// ---------------------------------------------------------------------------
// K3: out = relu(S + P0 + P1), vectorized f32x4. 512 blocks x 256 threads.
// ---------------------------------------------------------------------------
__global__ __launch_bounds__(256) void k3_reduce(
    const float* __restrict__ S, const float* __restrict__ P,
    float* __restrict__ out) {
  const int idx = blockIdx.x * 1024 + threadIdx.x * 4;
  f32x4 sv = *(const f32x4*)(S + idx);
  f32x4 p0 = *(const f32x4*)(P + idx);
  f32x4 p1 = *(const f32x4*)(P + TOTE + idx);
  f32x4 v = sv + p0 + p1;
  f32x4 o;
#pragma unroll
  for (int e = 0; e < 4; ++e) o[e] = v[e] > 0.f ? v[e] : 0.f;
  *(f32x4*)(out + idx) = o;
}

extern "C" void kernel_launch(void* const* d_in, const int* in_sizes, int n_in,
                              void* d_out, int out_size, void* d_ws, size_t ws_size,
                              hipStream_t stream) {
  const float* V  = (const float*)d_in[0];
  const float* A  = (const float*)d_in[1];
  const float* hw = (const float*)d_in[2];
  float* out = (float*)d_out;

  // ws layout: S (2 MB fp32) | Ut3 (3 MB bf16) | P (2 x 2 MB fp32)
  float* S = (float*)d_ws;
  unsigned short* Ut3 =
      (unsigned short*)((char*)d_ws + (size_t)TOTE * sizeof(float));
  float* P = (float*)((char*)d_ws + (size_t)TOTE * sizeof(float) +
                      (size_t)BDIM * BTOT * sizeof(unsigned short));

  k1_precompute<<<dim3(NDIM / 16, LDIM + 1, BDIM), 64, 0, stream>>>(V, hw, S, Ut3);
  k2_main<<<dim3(512), 512, 0, stream>>>(A, Ut3, P);
  k3_reduce<<<dim3(512), 256, 0, stream>>>(S, P, out);
}

// Round 13
// 46.542 us; speedup vs baseline: 1.3211x; 1.0498x over previous
//
#include <hip/hip_runtime.h>
#include <cstdint>

#define BDIM 4
#define NDIM 2048
#define FDIM 64
#define CDIM 64
#define LDIM 3
#define KTOT (NDIM * LDIM)   /* 6144 */
#define BK 256
#define NSTEP (KTOT / BK)    /* 24 */
#define KB (KTOT / 32)       /* 192 */
#define BSTEP (8 * 2048)     /* B shorts per step */
#define BTOT (KB * 2048)     /* B shorts per batch */

typedef __attribute__((ext_vector_type(4))) float f32x4;
typedef __attribute__((ext_vector_type(8))) short s16x8;
typedef __attribute__((ext_vector_type(4))) unsigned int u32x4;

__device__ __forceinline__ unsigned short f2bf(float x) {
  union { float f; uint32_t u; } v; v.f = x;
  uint32_t r = v.u + 0x7FFFu + ((v.u >> 16) & 1u);
  return (unsigned short)(r >> 16);
}

__device__ __forceinline__ uint32_t cvtpk(float lo, float hi) {
  uint32_t r;
  asm("v_cvt_pk_bf16_f32 %0, %1, %2" : "=v"(r) : "v"(lo), "v"(hi));
  return r;
}

// ---------------------------------------------------------------------------
// K1: S[b,i,c] = sum_f h0[c,f] V[b,i,f]   (fp32, ws)
//     Ut3[b][kb][cw][g][q][e] = U[b][c=cw*16+q][k=kb*32+g*8+e]  (bf16, ws)
// 256-thread blocks: wave wv handles j-tile j0 = blockIdx.x*64 + wv*16
// (same per-wave math as the R1-R12 verified version; grid 2048->512).
// MFMA 16x16x32 lane maps (verified R1-R12, absmax 0.5):
//   A: row=l&15, k=(l>>4)*8+e ; B: col=l&15, same k ; D: col=l&15, row=(l>>4)*4+rr
// ---------------------------------------------------------------------------
__global__ __launch_bounds__(256) void k1_precompute(
    const float* __restrict__ V, const float* __restrict__ hw,
    float* __restrict__ S, unsigned short* __restrict__ Ut3) {
  const int wv = threadIdx.x >> 6;
  const int j0 = blockIdx.x * 64 + wv * 16;
  const int le = blockIdx.y;
  const int b  = blockIdx.z;
  const int lane = threadIdx.x & 63;
  const int q = lane & 15, g = lane >> 4;

  const float* vrow = V + ((size_t)(b * NDIM + j0 + q)) * FDIM + g * 8;
  f32x4 va0 = *(const f32x4*)(vrow);
  f32x4 va1 = *(const f32x4*)(vrow + 4);
  f32x4 va2 = *(const f32x4*)(vrow + 32);
  f32x4 va3 = *(const f32x4*)(vrow + 36);
  s16x8 a0, a1;
#pragma unroll
  for (int e = 0; e < 4; ++e) {
    a0[e]     = (short)f2bf(va0[e]);
    a0[e + 4] = (short)f2bf(va1[e]);
    a1[e]     = (short)f2bf(va2[e]);
    a1[e + 4] = (short)f2bf(va3[e]);
  }

  const float* hbase = hw + (size_t)le * CDIM * FDIM;
#pragma unroll
  for (int ct = 0; ct < 4; ++ct) {
    const float* hrow = hbase + (size_t)(ct * 16 + q) * FDIM + g * 8;
    f32x4 hb0 = *(const f32x4*)(hrow);
    f32x4 hb1 = *(const f32x4*)(hrow + 4);
    f32x4 hb2 = *(const f32x4*)(hrow + 32);
    f32x4 hb3 = *(const f32x4*)(hrow + 36);
    s16x8 b0, b1;
#pragma unroll
    for (int e = 0; e < 4; ++e) {
      b0[e]     = (short)f2bf(hb0[e]);
      b0[e + 4] = (short)f2bf(hb1[e]);
      b1[e]     = (short)f2bf(hb2[e]);
      b1[e + 4] = (short)f2bf(hb3[e]);
    }
    f32x4 acc = {0.f, 0.f, 0.f, 0.f};
    acc = __builtin_amdgcn_mfma_f32_16x16x32_bf16(a0, b0, acc, 0, 0, 0);
    acc = __builtin_amdgcn_mfma_f32_16x16x32_bf16(a1, b1, acc, 0, 0, 0);
    if (le == 0) {
#pragma unroll
      for (int rr = 0; rr < 4; ++rr) {
        int j = j0 + g * 4 + rr;
        S[((size_t)b * NDIM + j) * CDIM + ct * 16 + q] = acc[rr];
      }
    } else {
#pragma unroll
      for (int rr = 0; rr < 4; ++rr) {
        int j = j0 + g * 4 + rr;
        int k = j * 3 + (le - 1);
        int kb = k >> 5, gg = (k >> 3) & 3, ee = k & 7;
        size_t off = ((size_t)b * KB + kb) * 2048 + (size_t)ct * 512 +
                     (size_t)gg * 128 + (size_t)q * 8 + ee;
        Ut3[off] = f2bf(acc[rr]);
      }
    }
  }
}

// ---------------------------------------------------------------------------
// K2: out[b, i0..i0+31, :] = relu(S + A[b,i0:i0+32,:] @ U[b])
// EXACT R10 (best: 46.5 us): M=32, 8 waves, BK=256/step, 24 steps,
// grid 256 = 1 block/CU. Wave (wr,wc)=(w>>2,w&3): rows wr*16..+15,
// cols wc*16..+15; wr-paired waves load identical B lines barrier-synced.
// A: 1 KB GLL granules (the only lever that mattered: R5 256B=60us,
//    R6 1KB=48us, R8 2KB=null), wave w stages rows 4w..4w+3; 16B granules
//    XOR-preswizzled by row&7 (involution; read applies same).
// Ring 2 x 32 KB slots (64 KB static), GLL ahead-1, 2 barriers/step.
// Counted waits both vmcnt(8) (12 vmem ops/step = 4 GLL + 8 B):
//   pos3: retires GLL(s)+B_H0(s), keeps {B_H1(s), GLL(s+1)};
//   pos7: retires B_H1(s), keeps {GLL(s+1), B_H0(s+1)}.
// NEVER vmcnt(0) in the loop. A-read pins at ~4.8 TB/s = measured pattern
// ceiling for 24KB-strided row-streams (granule/TLP/phase/depth all null).
// ---------------------------------------------------------------------------
__global__ __launch_bounds__(512) void k2_main(
    const float* __restrict__ A, const unsigned short* __restrict__ Ut3,
    const float* __restrict__ S, float* __restrict__ out) {
  __shared__ float Abuf[2][8192];  // 2 slots x 32 rows x 256 floats = 64 KB

  const int bid = blockIdx.x;
  const int swz = (bid & 7) * 32 + (bid >> 3);  // XCD-chunked, 256 % 8 == 0
  const int b   = swz >> 6;
  const int i0  = (swz & 63) * 32;
  const int tid = threadIdx.x;
  const int lane = tid & 63, w = tid >> 6;
  const int q = lane & 15, g = lane >> 4, q7 = q & 7;
  const int wr = w >> 2, wc = w & 3;

  const float* agb[4];
#pragma unroll
  for (int t = 0; t < 4; ++t) {
    int r = 4 * w + t;
    agb[t] = A + ((size_t)(b * NDIM + i0 + r)) * KTOT + ((lane ^ (r & 7)) * 4);
  }
  int akoff = 0;

  const unsigned short* bgb =
      Ut3 + (size_t)b * BTOT + (size_t)wc * 512 + (size_t)lane * 8;
  int bkoff = 0;

  float* ldsw = &Abuf[0][0] + w * 1024 + lane * 4;

#define GLL4(slot)                                                            \
  do {                                                                        \
    __builtin_amdgcn_global_load_lds(                                         \
        (__attribute__((address_space(1))) void*)(agb[0] + akoff),            \
        (__attribute__((address_space(3))) void*)(ldsw + (slot) * 8192), 16, 0, 0); \
    __builtin_amdgcn_global_load_lds(                                         \
        (__attribute__((address_space(1))) void*)(agb[1] + akoff),            \
        (__attribute__((address_space(3))) void*)(ldsw + (slot) * 8192 + 256), 16, 0, 0); \
    __builtin_amdgcn_global_load_lds(                                         \
        (__attribute__((address_space(1))) void*)(agb[2] + akoff),            \
        (__attribute__((address_space(3))) void*)(ldsw + (slot) * 8192 + 512), 16, 0, 0); \
    __builtin_amdgcn_global_load_lds(                                         \
        (__attribute__((address_space(1))) void*)(agb[3] + akoff),            \
        (__attribute__((address_space(3))) void*)(ldsw + (slot) * 8192 + 768), 16, 0, 0); \
  } while (0)

#define LDB(BW, HB)                                                           \
  do {                                                                        \
    _Pragma("unroll")                                                         \
    for (int t = 0; t < 4; ++t)                                               \
      BW[t] = *(const s16x8*)(bgb + bkoff + (size_t)((HB) + t) * 2048);       \
  } while (0)

#define HALF(half, BR)                                                        \
  do {                                                                        \
    const float* rowp = &Abuf[s & 1][0] + (wr * 16 + q) * 256;                \
    _Pragma("unroll")                                                         \
    for (int kk = 0; kk < 4; ++kk) {                                          \
      int kg = (half) * 4 + kk;                                               \
      f32x4 a0 = *(const f32x4*)(rowp + ((kg * 8 + ((2 * g) ^ q7)) << 2));    \
      f32x4 a1 = *(const f32x4*)(rowp + ((kg * 8 + ((2 * g + 1) ^ q7)) << 2));\
      u32x4 wv;                                                               \
      wv[0] = cvtpk(a0[0], a0[1]); wv[1] = cvtpk(a0[2], a0[3]);               \
      wv[2] = cvtpk(a1[0], a1[1]); wv[3] = cvtpk(a1[2], a1[3]);               \
      if (kk & 1)                                                             \
        accB = __builtin_amdgcn_mfma_f32_16x16x32_bf16(                       \
            __builtin_bit_cast(s16x8, wv), BR[kk], accB, 0, 0, 0);            \
      else                                                                    \
        accA = __builtin_amdgcn_mfma_f32_16x16x32_bf16(                       \
            __builtin_bit_cast(s16x8, wv), BR[kk], accA, 0, 0, 0);            \
    }                                                                         \
  } while (0)

  f32x4 accA = {0.f, 0.f, 0.f, 0.f}, accB = {0.f, 0.f, 0.f, 0.f};
  s16x8 bA[4], bB[4];

  // prologue: GLL(0)x4, B_H0(0)x4 -> bA; akoff advances to step 1
  GLL4(0); akoff = BK;
  LDB(bA, 0);

  for (int s = 0; s < NSTEP; ++s) {
    LDB(bB, 4);                           // B_H1(s)
    GLL4((s + 1) & 1);                    // A(s+1) -> other slot
    if (s + 2 < NSTEP) akoff += BK;       // tail: freeze (dead slot re-read)
    if (s + 1 < NSTEP) bkoff += BSTEP;    // -> step s+1's B base
    asm volatile("s_waitcnt vmcnt(8)" ::: "memory");  // A(s), B_H0(s) done
    __builtin_amdgcn_sched_barrier(0);
    __builtin_amdgcn_s_barrier();         // A(s) visible to all waves
    __builtin_amdgcn_sched_barrier(0);
    HALF(0, bA);                          // kb 0..3
    LDB(bA, 0);                           // B_H0(s+1) (s=23: dead re-read)
    asm volatile("s_waitcnt vmcnt(8)" ::: "memory");  // B_H1(s) done
    __builtin_amdgcn_sched_barrier(0);
    HALF(1, bB);                          // kb 4..7
    __builtin_amdgcn_s_barrier();         // end-of-step: protect slot (s+1)&1
  }
#undef HALF
#undef GLL4
#undef LDB

  asm volatile("s_waitcnt vmcnt(0)" ::: "memory");

  f32x4 acc = accA + accB;
  const int c = wc * 16 + q;
#pragma unroll
  for (int rr = 0; rr < 4; ++rr) {
    int i = i0 + wr * 16 + g * 4 + rr;
    size_t idx = ((size_t)(b * NDIM) + i) * CDIM + c;
    float v = acc[rr] + S[idx];
    out[idx] = v > 0.f ? v : 0.f;
  }
}

extern "C" void kernel_launch(void* const* d_in, const int* in_sizes, int n_in,
                              void* d_out, int out_size, void* d_ws, size_t ws_size,
                              hipStream_t stream) {
  const float* V  = (const float*)d_in[0];
  const float* A  = (const float*)d_in[1];
  const float* hw = (const float*)d_in[2];
  float* out = (float*)d_out;

  float* S = (float*)d_ws;
  unsigned short* Ut3 =
      (unsigned short*)((char*)d_ws + (size_t)BDIM * NDIM * CDIM * sizeof(float));

  k1_precompute<<<dim3(NDIM / 64, LDIM + 1, BDIM), 256, 0, stream>>>(V, hw, S, Ut3);
  k2_main<<<dim3((NDIM / 32) * BDIM), 512, 0, stream>>>(A, Ut3, S, out);
}